// Round 1
// 596.711 us; speedup vs baseline: 1.1234x; 1.1234x over previous
//
#include <hip/hip_runtime.h>

// StackMemory fused pipeline for MI355X (gfx950).
// B=4, S=2048, H=1024, NH=16, SLOTS=16, SD=32, HD=64. 8192 tokens.
//
// Restructure vs previous version (309 us main dispatch, latency-bound):
//   proj_kernel : actions logits (raw) + k projection for all tokens,
//                 stashed into the new_stack OUTPUT region (slot0 = k,
//                 slot1[0:3] = logits). Each (tok,head) slice is read then
//                 fully overwritten by the SAME wave in stack_main, so the
//                 stash needs no extra workspace and has no cross-wave race.
//   stack_main  : one wave per (token, head). Lane l holds float4
//                 (slot = l>>3, quarter = l&7). 1KB fully-coalesced global
//                 loads/stores, slot-shift via lane shuffles, gate/softmax/
//                 mem-reduce via xor butterflies, 512 B LDS, one barrier.
//
// Outputs concatenated flat: out [8192*1024] | new_stack [8192*8192] | new_mask [8192*256]

constexpr long long OUT_STACK_OFF = 8388608LL;     // 4*2048*1024
constexpr long long OUT_MASK_OFF  = 75497472LL;    // + 4*2048*16*16*32

__global__ void transpose_wa(const float* __restrict__ Wa, float* __restrict__ WaT) {
    int o = blockIdx.x * 256 + threadIdx.x;        // 48*1024 elements
    if (o < 48 * 1024) {
        int j = o >> 10, i = o & 1023;
        WaT[o] = Wa[i * 48 + j];
    }
}

__device__ __forceinline__ float dot4(float4 a, float4 b) {
    return a.x * b.x + a.y * b.y + a.z * b.z + a.w * b.w;
}

__device__ __forceinline__ float4 shfl4(float4 v, int src) {
    return make_float4(__shfl(v.x, src), __shfl(v.y, src),
                       __shfl(v.z, src), __shfl(v.w, src));
}

__device__ __forceinline__ float4 sel4(bool c, float4 a, float4 b) {
    return make_float4(c ? a.x : b.x, c ? a.y : b.y, c ? a.z : b.z, c ? a.w : b.w);
}

// ---------------------------------------------------------------------------
// Phase 1: raw scaled logits + k projection, 4 tokens per block (amortizes
// the 192 KB WaT read 4x). No LDS at all -> high residency.
// ---------------------------------------------------------------------------
__global__ __launch_bounds__(256)
void proj_kernel(const float* __restrict__ hid,
                 const float* __restrict__ WaT,   // [48][1024]
                 const float* __restrict__ ba,    // [48]
                 const float* __restrict__ Wd,    // [64][32]
                 const float* __restrict__ bd,    // [32]
                 float* __restrict__ out)
{
    const int t = threadIdx.x;
    const int wv = t >> 6, lane = t & 63;
    const int tok0 = blockIdx.x * 4;
    float* stash = out + OUT_STACK_OFF;
    const float4* hid4 = (const float4*)hid + (size_t)tok0 * 256;

    // cache 4 tokens' hidden rows across lanes: lane covers floats 4*(m*64+lane)
    float4 hreg[4][4];
    #pragma unroll
    for (int tt = 0; tt < 4; ++tt)
        #pragma unroll
        for (int m = 0; m < 4; ++m)
            hreg[tt][m] = hid4[tt * 256 + m * 64 + lane];

    // ---- logits: wave wv computes j in [12wv, 12wv+12) for all 4 tokens ----
    const float4* waT4 = (const float4*)WaT;
    #pragma unroll
    for (int jj = 0; jj < 12; ++jj) {
        int j = wv * 12 + jj;
        float a0 = 0.f, a1 = 0.f, a2 = 0.f, a3 = 0.f;
        #pragma unroll
        for (int m = 0; m < 4; ++m) {
            float4 w = waT4[j * 256 + m * 64 + lane];
            a0 += dot4(hreg[0][m], w);
            a1 += dot4(hreg[1][m], w);
            a2 += dot4(hreg[2][m], w);
            a3 += dot4(hreg[3][m], w);
        }
        #pragma unroll
        for (int off = 1; off <= 32; off <<= 1) {
            a0 += __shfl_xor(a0, off);
            a1 += __shfl_xor(a1, off);
            a2 += __shfl_xor(a2, off);
            a3 += __shfl_xor(a3, off);
        }
        if ((lane & 15) == jj) {                 // lanes jj, jj+16, jj+32, jj+48
            int tt = lane >> 4;
            float v = (tt == 0) ? a0 : (tt == 1) ? a1 : (tt == 2) ? a2 : a3;
            int nh = wv * 4 + jj / 3, a = jj - 3 * (jj / 3);
            stash[(size_t)(tok0 + tt) * 8192 + nh * 512 + 32 + a] = (v + ba[j]) * 0.125f;
        }
    }

    // ---- k projection: thread -> dim d = t&31, heads nhg and nhg+8, 4 tokens ----
    const int d = t & 31, nhg = t >> 5;
    float acc0[4], acc1[4];
    float bdv = bd[d];
    #pragma unroll
    for (int tt = 0; tt < 4; ++tt) { acc0[tt] = bdv; acc1[tt] = bdv; }
    #pragma unroll
    for (int ii = 0; ii < 16; ++ii) {
        float w0 = Wd[(4 * ii + 0) * 32 + d];
        float w1 = Wd[(4 * ii + 1) * 32 + d];
        float w2 = Wd[(4 * ii + 2) * 32 + d];
        float w3 = Wd[(4 * ii + 3) * 32 + d];
        #pragma unroll
        for (int tt = 0; tt < 4; ++tt) {
            float4 ha = hid4[tt * 256 + nhg * 16 + ii];        // broadcast, L1-hot
            float4 hb = hid4[tt * 256 + (nhg + 8) * 16 + ii];
            acc0[tt] += ha.x * w0 + ha.y * w1 + ha.z * w2 + ha.w * w3;
            acc1[tt] += hb.x * w0 + hb.y * w1 + hb.z * w2 + hb.w * w3;
        }
    }
    #pragma unroll
    for (int tt = 0; tt < 4; ++tt) {
        stash[(size_t)(tok0 + tt) * 8192 + nhg * 512 + d] = acc0[tt];
        stash[(size_t)(tok0 + tt) * 8192 + (nhg + 8) * 512 + d] = acc1[tt];
    }
}

// ---------------------------------------------------------------------------
// Phase 2: one wave per (token, head). Lane l <-> float4 (slot=l>>3, q=l&7).
// ---------------------------------------------------------------------------
__global__ __launch_bounds__(256, 4)
void stack_main(const float* __restrict__ stack,
                const float* __restrict__ mask,
                const float* __restrict__ hid,
                const float* __restrict__ Wg,    // [32]
                const float* __restrict__ bgp,   // [1]
                const float* __restrict__ Wu,    // [32][64]
                const float* __restrict__ bu,    // [64]
                const float* __restrict__ resw,  // [1]
                float* __restrict__ out)
{
    __shared__ __align__(16) float sh_mem[4][32];
    const int t = threadIdx.x, wv = t >> 6, l = t & 63;
    const int wid = blockIdx.x * 4 + wv;
    const int tok = wid >> 4, nh = wid & 15;

    const float4* stk4 = (const float4*)stack + (size_t)tok * 2048 + nh * 128;
    float* ostack = out + OUT_STACK_OFF + (size_t)tok * 8192 + nh * 512;
    const float4* stash4 = (const float4*)ostack;

    float4 A  = stk4[l];           // slots 0..7   (1 KB coalesced)
    float4 Bv = stk4[64 + l];      // slots 8..15
    float4 kv = stash4[l & 7];     // k[nh] quarter (stash; overwritten below by THIS wave)
    float4 lg = stash4[8];         // raw logits in .x .y .z (broadcast)
    const float* mrow_g = mask + (size_t)tok * 256 + nh * 16;
    float mA = mrow_g[l >> 3];
    float mB = mrow_g[8 + (l >> 3)];
    float4 wg = *(const float4*)(Wg + (l & 7) * 4);

    // action softmax (uniform across wave)
    float mx = fmaxf(lg.x, fmaxf(lg.y, lg.z));
    float e0 = __expf(lg.x - mx), e1 = __expf(lg.y - mx), e2 = __expf(lg.z - mx);
    float ainv = 1.f / (e0 + e1 + e2);
    float ap = e0 * ainv, apop = e1 * ainv, an = e2 * ainv;

    // neighbor rows: slot stride = 8 lanes (shuffles unconditional = convergent)
    float4 Am  = shfl4(A,  l - 8);   // slot-1 within A
    float4 Apl = shfl4(A,  l + 8);   // slot+1 within A
    float4 BfA = shfl4(A,  l + 56);  // slot7 -> prev of slot8 (lanes l<8)
    float4 AfB = shfl4(Bv, l - 56);  // slot8 -> next of slot7 (lanes l>=56)
    float4 Bm  = shfl4(Bv, l - 8);
    float4 Bp  = shfl4(Bv, l + 8);
    float sAm = __shfl(mA, l - 8), sAp = __shfl(mA, l + 8), sA56 = __shfl(mA, l + 56);
    float sBm = __shfl(mB, l - 8), sBp = __shfl(mB, l + 8), sB56 = __shfl(mB, l - 56);

    const bool lo = (l < 8), hi = (l >= 56);
    float4 prevA = sel4(lo, kv, Am);
    float4 nextA = sel4(hi, AfB, Apl);
    float4 prevB = sel4(lo, BfA, Bm);
    float4 nextB = sel4(hi, make_float4(0.f, 0.f, 0.f, 0.f), Bp);
    float pmA = lo ? 1.f : sAm;
    float nmA = hi ? sB56 : sAp;
    float pmB = lo ? sA56 : sBm;
    float nmB = hi ? 0.f : sBp;

    float4 nA, nB;
    nA.x = ap * prevA.x + apop * nextA.x + an * A.x;
    nA.y = ap * prevA.y + apop * nextA.y + an * A.y;
    nA.z = ap * prevA.z + apop * nextA.z + an * A.z;
    nA.w = ap * prevA.w + apop * nextA.w + an * A.w;
    nB.x = ap * prevB.x + apop * nextB.x + an * Bv.x;
    nB.y = ap * prevB.y + apop * nextB.y + an * Bv.y;
    nB.z = ap * prevB.z + apop * nextB.z + an * Bv.z;
    nB.w = ap * prevB.w + apop * nextB.w + an * Bv.w;
    float nmaskA = ap * pmA + apop * nmA + an * mA;
    float nmaskB = ap * pmB + apop * nmB + an * mB;

    // store new_stack: two 1 KB coalesced instructions (overwrites the stash;
    // safe: store data depends on kv/lg loads -> HW orders load before store)
    float4* ost4 = (float4*)ostack;
    ost4[l] = nA;
    ost4[64 + l] = nB;
    if ((l & 7) == 0) {
        float* om = out + OUT_MASK_OFF + (size_t)tok * 256 + nh * 16;
        om[l >> 3] = nmaskA;
        om[8 + (l >> 3)] = nmaskB;
    }

    // gate scores: dot over d (reduce quarters, xor 1/2/4 within slot group)
    float gA = dot4(nA, wg);
    float gB = dot4(nB, wg);
    #pragma unroll
    for (int off = 1; off <= 4; off <<= 1) {
        gA += __shfl_xor(gA, off);
        gB += __shfl_xor(gB, off);
    }
    float bgv = bgp[0];
    gA += bgv + (1.f - nmaskA) * -1e9f;
    gB += bgv + (1.f - nmaskB) * -1e9f;

    // softmax over 16 slots (xor 8/16/32 spans all slot groups)
    float gm = fmaxf(gA, gB);
    #pragma unroll
    for (int off = 8; off <= 32; off <<= 1) gm = fmaxf(gm, __shfl_xor(gm, off));
    float eA = __expf(gA - gm), eB = __expf(gB - gm);
    float es = eA + eB;
    #pragma unroll
    for (int off = 8; off <= 32; off <<= 1) es += __shfl_xor(es, off);
    float ginv = 1.f / es;
    float gateA = eA * ginv, gateB = eB * ginv;

    // mem[d] = sum_slots gate * new_row  (butterfly over slot groups)
    float4 sv;
    sv.x = gateA * nA.x + gateB * nB.x;
    sv.y = gateA * nA.y + gateB * nB.y;
    sv.z = gateA * nA.z + gateB * nB.z;
    sv.w = gateA * nA.w + gateB * nB.w;
    #pragma unroll
    for (int off = 8; off <= 32; off <<= 1) {
        sv.x += __shfl_xor(sv.x, off);
        sv.y += __shfl_xor(sv.y, off);
        sv.z += __shfl_xor(sv.z, off);
        sv.w += __shfl_xor(sv.w, off);
    }
    if (l < 8) *(float4*)&sh_mem[wv][l * 4] = sv;   // mem quarter l
    __syncthreads();

    // out = mem @ Wu + bu, * res_weight + hidden; lane -> output element l
    float acc = bu[l];
    const float* mrow = sh_mem[wv];
    #pragma unroll
    for (int dd = 0; dd < 32; ++dd)
        acc += mrow[dd] * Wu[dd * 64 + l];          // LDS broadcast + 256B coalesced load
    size_t oidx = (size_t)tok * 1024 + nh * 64 + l;
    out[oidx] = acc * resw[0] + hid[oidx];
}

extern "C" void kernel_launch(void* const* d_in, const int* in_sizes, int n_in,
                              void* d_out, int out_size, void* d_ws, size_t ws_size,
                              hipStream_t stream) {
    const float* hid  = (const float*)d_in[0];
    const float* stk  = (const float*)d_in[1];
    const float* msk  = (const float*)d_in[2];
    const float* Wa   = (const float*)d_in[3];
    const float* ba   = (const float*)d_in[4];
    const float* Wd   = (const float*)d_in[5];
    const float* bd   = (const float*)d_in[6];
    const float* Wu   = (const float*)d_in[7];
    const float* bu   = (const float*)d_in[8];
    const float* Wg   = (const float*)d_in[9];
    const float* bg   = (const float*)d_in[10];
    const float* rw   = (const float*)d_in[11];
    float* out = (float*)d_out;
    float* waT = (float*)d_ws;   // 48*1024 floats = 192 KiB scratch

    transpose_wa<<<192, 256, 0, stream>>>(Wa, waT);
    proj_kernel<<<2048, 256, 0, stream>>>(hid, waT, ba, Wd, bd, out);
    stack_main<<<32768, 256, 0, stream>>>(stk, msk, hid, Wg, bg, Wu, bu, rw, out);
}